// Round 3
// baseline (722.323 us; speedup 1.0000x reference)
//
#include <hip/hip_runtime.h>
#include <stdint.h>

// ResBlock: GraphConv(64->128) -> BN -> ReLU -> GraphConv(128->128) -> BN
//           + (x @ Wlin^T + blin) residual -> ReLU.
// Runtime dtype probe (bf16 vs f32). CSR-by-dst per call.
// R2->R3: de-fused gather. Wave-per-node aggregation kernels with fully
// coalesced row loads (256B/instr) + neighbor unroll x4 for MLP; GEMMs dense.

#define CIN 64
#define COUT 128
#define BN_EPS 1e-5f

typedef unsigned short u16;
typedef short short8 __attribute__((ext_vector_type(8)));
typedef float f32x4 __attribute__((ext_vector_type(4)));

__device__ __forceinline__ float bf2f(u16 u) {
    union { unsigned int i; float f; } v; v.i = ((unsigned int)u) << 16; return v.f;
}
__device__ __forceinline__ u16 f2bf(float f) {
    union { float f; unsigned int i; } v; v.f = f;
    unsigned int r = v.i + 0x7fffu + ((v.i >> 16) & 1u);  // RNE; finite inputs
    return (u16)(r >> 16);
}
__device__ __forceinline__ float lo16(unsigned int w) { return bf2f((u16)(w & 0xffffu)); }
__device__ __forceinline__ float hi16(unsigned int w) { return bf2f((u16)(w >> 16)); }

// dtype-generic loads ------------------------------------------------------
template<bool BF> __device__ __forceinline__ float ldf(const void* p, long i) {
    if (BF) return bf2f(((const u16*)p)[i]);
    return ((const float*)p)[i];
}
template<bool BF> __device__ __forceinline__ short8 ld8(const void* p, long i) {
    if (BF) return *(const short8*)((const u16*)p + i);
    const float* f = (const float*)p + i;
    short8 r;
#pragma unroll
    for (int j = 0; j < 8; ++j) r[j] = (short)f2bf(f[j]);
    return r;
}

// ---------------- dtype detection ----------------
__global__ void k_detect(const unsigned int* __restrict__ x, int* __restrict__ flag) {
    int lane = threadIdx.x;  // 64
    int cnt = 0;
#pragma unroll
    for (int i = 0; i < 8; ++i) {
        unsigned int w = x[lane * 8 + i];
        unsigned int e0 = (w >> 7) & 0xFFu, e1 = (w >> 23) & 0xFFu;
        cnt += (e0 >= 0x60u && e0 <= 0x8Eu);
        cnt += (e1 >= 0x60u && e1 <= 0x8Eu);
    }
    for (int o = 32; o; o >>= 1) cnt += __shfl_down(cnt, o);
    if (lane == 0) *flag = (cnt > 850) ? 1 : 0;   // 1 => bf16
}

// ---------------- CSR build ----------------
__global__ void k_hist(const int* __restrict__ dst, int* __restrict__ deg, int E) {
    int e = blockIdx.x * blockDim.x + threadIdx.x;
    if (e < E) atomicAdd(&deg[dst[e]], 1);
}

__global__ void k_scan1(const int* __restrict__ deg, int* __restrict__ blksum, int n) {
    __shared__ int s[256];
    int t = threadIdx.x, i = blockIdx.x * 256 + t;
    int v = (i < n) ? deg[i] : 0;
    s[t] = v; __syncthreads();
    for (int o = 1; o < 256; o <<= 1) {
        int u = (t >= o) ? s[t - o] : 0;
        __syncthreads(); s[t] += u; __syncthreads();
    }
    if (t == 255) blksum[blockIdx.x] = s[255];
}

__global__ void k_scan2(const int* __restrict__ blksum, int* __restrict__ blkoff, int nb) {
    __shared__ int s[512];
    int t = threadIdx.x;
    int v = (t < nb) ? blksum[t] : 0;
    s[t] = v; __syncthreads();
    for (int o = 1; o < 512; o <<= 1) {
        int u = (t >= o) ? s[t - o] : 0;
        __syncthreads(); s[t] += u; __syncthreads();
    }
    if (t < nb) blkoff[t] = s[t] - v;  // exclusive
}

__global__ void k_scan3(const int* __restrict__ deg, const int* __restrict__ blkoff,
                        int* __restrict__ row_start, int n) {
    __shared__ int s[256];
    int t = threadIdx.x, i = blockIdx.x * 256 + t;
    int v = (i < n) ? deg[i] : 0;
    s[t] = v; __syncthreads();
    for (int o = 1; o < 256; o <<= 1) {
        int u = (t >= o) ? s[t - o] : 0;
        __syncthreads(); s[t] += u; __syncthreads();
    }
    int base = blkoff[blockIdx.x];
    if (i < n) row_start[i] = base + s[t] - v;
    if (i == n - 1) row_start[n] = base + s[t];
}

__global__ void k_fill(const int* __restrict__ src, const int* __restrict__ dst,
                       const int* __restrict__ row_start, int* __restrict__ cursor,
                       int* __restrict__ csr, int E) {
    int e = blockIdx.x * blockDim.x + threadIdx.x;
    if (e < E) {
        int d = dst[e];
        int p = atomicAdd(&cursor[d], 1);
        csr[row_start[d] + p] = src[e];
    }
}

// ---------------- aggregation: wave per node, coalesced row loads ---------
// agg0: x rows are 64 cols. Half-wave h loads neighbor t+h; lane&31 = col pair.
template<bool BF>
__device__ __forceinline__ void agg0_impl(const void* x, const int* rs, const int* csr,
                                          u16* agg, int n) {
    int i = blockIdx.x * 4 + (threadIdx.x >> 6);
    if (i >= n) return;
    int lane = threadIdx.x & 63;
    int h = lane >> 5, cp = lane & 31;
    int b = rs[i], e = rs[i + 1];
    float a0 = 0.f, a1 = 0.f, b0 = 0.f, b1 = 0.f;
    int t = b + h;
    for (; t + 2 < e; t += 4) {  // 2 neighbors per half-wave step (unroll x2)
        int j0 = csr[t], j1 = csr[t + 2];
        if (BF) {
            unsigned int w0 = ((const unsigned int*)x)[(long)j0 * 32 + cp];
            unsigned int w1 = ((const unsigned int*)x)[(long)j1 * 32 + cp];
            a0 += lo16(w0); a1 += hi16(w0);
            b0 += lo16(w1); b1 += hi16(w1);
        } else {
            float2 w0 = ((const float2*)x)[(long)j0 * 32 + cp];
            float2 w1 = ((const float2*)x)[(long)j1 * 32 + cp];
            a0 += w0.x; a1 += w0.y;
            b0 += w1.x; b1 += w1.y;
        }
    }
    for (; t < e; t += 2) {
        int j0 = csr[t];
        if (BF) {
            unsigned int w0 = ((const unsigned int*)x)[(long)j0 * 32 + cp];
            a0 += lo16(w0); a1 += hi16(w0);
        } else {
            float2 w0 = ((const float2*)x)[(long)j0 * 32 + cp];
            a0 += w0.x; a1 += w0.y;
        }
    }
    a0 += b0; a1 += b1;
    a0 += __shfl_xor(a0, 32);  // combine the two half-wave partial sums
    a1 += __shfl_xor(a1, 32);
    if (h == 0) {
        unsigned int o = (unsigned int)f2bf(a0) | ((unsigned int)f2bf(a1) << 16);
        ((unsigned int*)agg)[(long)i * 32 + cp] = o;
    }
}

__global__ __launch_bounds__(256) void k_agg0(const int* __restrict__ flag,
        const void* x, const int* __restrict__ rs, const int* __restrict__ csr,
        u16* __restrict__ agg, int n) {
    if (*flag) agg0_impl<true >(x, rs, csr, agg, n);
    else       agg0_impl<false>(x, rs, csr, agg, n);
}

// agg1: y0' rows are 128 cols = 64 lanes x u32 (one 256B coalesced load/row).
// Neighbor unroll x4 for MLP. y0' is always internal bf16.
__global__ __launch_bounds__(256) void k_agg1(const u16* __restrict__ y0,
        const int* __restrict__ rs, const int* __restrict__ csr,
        u16* __restrict__ agg, int n) {
    int i = blockIdx.x * 4 + (threadIdx.x >> 6);
    if (i >= n) return;
    int lane = threadIdx.x & 63;
    const unsigned int* y32 = (const unsigned int*)y0;
    int b = rs[i], e = rs[i + 1];
    float a0 = 0.f, a1 = 0.f, b0 = 0.f, b1 = 0.f;
    float c0 = 0.f, c1 = 0.f, d0 = 0.f, d1 = 0.f;
    int t = b;
    for (; t + 4 <= e; t += 4) {
        int j0 = csr[t], j1 = csr[t + 1], j2 = csr[t + 2], j3 = csr[t + 3];
        unsigned int w0 = y32[(long)j0 * 64 + lane];
        unsigned int w1 = y32[(long)j1 * 64 + lane];
        unsigned int w2 = y32[(long)j2 * 64 + lane];
        unsigned int w3 = y32[(long)j3 * 64 + lane];
        a0 += lo16(w0); a1 += hi16(w0);
        b0 += lo16(w1); b1 += hi16(w1);
        c0 += lo16(w2); c1 += hi16(w2);
        d0 += lo16(w3); d1 += hi16(w3);
    }
    for (; t < e; ++t) {
        unsigned int w0 = y32[(long)csr[t] * 64 + lane];
        a0 += lo16(w0); a1 += hi16(w0);
    }
    float s0 = (a0 + b0) + (c0 + d0);
    float s1 = (a1 + b1) + (c1 + d1);
    ((unsigned int*)agg)[(long)i * 64 + lane] =
        (unsigned int)f2bf(s0) | ((unsigned int)f2bf(s1) << 16);
}

// ---------------- dense GEMMs (mfma 16x16x32 bf16) ------------------------
// A: m=lane&15, k=(lane>>4)*8+j.  B: n=lane&15 (row of W).  D: col=lane&15, row=q*4+reg.
template<bool BF>
__device__ __forceinline__ void gemm0_impl(const void* x, const u16* agg,
                                           const void* Wr, const void* Wn,
                                           u16* y0, int ntiles, int n) {
    int tile = blockIdx.x * 4 + (threadIdx.x >> 6);
    if (tile >= ntiles) return;
    int lane = threadIdx.x & 63;
    int lr = lane & 15, q = lane >> 4;
    int m0 = tile * 16;
    int ra = m0 + lr; if (ra > n - 1) ra = n - 1;
    short8 ax0 = ld8<BF>(x, (long)ra * CIN + q * 8);
    short8 ax1 = ld8<BF>(x, (long)ra * CIN + 32 + q * 8);
    short8 ag0 = *(const short8*)(agg + (long)ra * CIN + q * 8);
    short8 ag1 = *(const short8*)(agg + (long)ra * CIN + 32 + q * 8);
#pragma unroll
    for (int ct = 0; ct < 8; ++ct) {
        int c = ct * 16 + lr;
        short8 br0 = ld8<BF>(Wr, (long)c * CIN + q * 8);
        short8 br1 = ld8<BF>(Wr, (long)c * CIN + 32 + q * 8);
        short8 bn0 = ld8<BF>(Wn, (long)c * CIN + q * 8);
        short8 bn1 = ld8<BF>(Wn, (long)c * CIN + 32 + q * 8);
        f32x4 acc = {0.f, 0.f, 0.f, 0.f};
        acc = __builtin_amdgcn_mfma_f32_16x16x32_bf16(ax0, br0, acc, 0, 0, 0);
        acc = __builtin_amdgcn_mfma_f32_16x16x32_bf16(ax1, br1, acc, 0, 0, 0);
        acc = __builtin_amdgcn_mfma_f32_16x16x32_bf16(ag0, bn0, acc, 0, 0, 0);
        acc = __builtin_amdgcn_mfma_f32_16x16x32_bf16(ag1, bn1, acc, 0, 0, 0);
#pragma unroll
        for (int r = 0; r < 4; ++r) {
            int row = m0 + q * 4 + r;
            if (row < n) y0[(long)row * COUT + c] = f2bf(acc[r]);  // b0 cancels in BN
        }
    }
}

__global__ __launch_bounds__(256) void k_gemm0(const int* __restrict__ flag,
        const void* x, const u16* __restrict__ agg, const void* Wr, const void* Wn,
        u16* __restrict__ y0, int ntiles, int n) {
    if (*flag) gemm0_impl<true >(x, agg, Wr, Wn, y0, ntiles, n);
    else       gemm0_impl<false>(x, agg, Wr, Wn, y0, ntiles, n);
}

template<bool BF>
__device__ __forceinline__ void gemm1_impl(const u16* y0, const u16* agg,
                                           const void* Wr, const void* Wn,
                                           u16* y1, int ntiles, int n) {
    int tile = blockIdx.x * 4 + (threadIdx.x >> 6);
    if (tile >= ntiles) return;
    int lane = threadIdx.x & 63;
    int lr = lane & 15, q = lane >> 4;
    int m0 = tile * 16;
    int ra = m0 + lr; if (ra > n - 1) ra = n - 1;
    short8 ay[4], ag[4];
#pragma unroll
    for (int ks = 0; ks < 4; ++ks) {
        ay[ks] = *(const short8*)(y0 + (long)ra * COUT + ks * 32 + q * 8);
        ag[ks] = *(const short8*)(agg + (long)ra * COUT + ks * 32 + q * 8);
    }
#pragma unroll
    for (int ct = 0; ct < 8; ++ct) {
        int c = ct * 16 + lr;
        f32x4 acc = {0.f, 0.f, 0.f, 0.f};
#pragma unroll
        for (int ks = 0; ks < 4; ++ks) {
            short8 br = ld8<BF>(Wr, (long)c * COUT + ks * 32 + q * 8);
            short8 bn = ld8<BF>(Wn, (long)c * COUT + ks * 32 + q * 8);
            acc = __builtin_amdgcn_mfma_f32_16x16x32_bf16(ay[ks], br, acc, 0, 0, 0);
            acc = __builtin_amdgcn_mfma_f32_16x16x32_bf16(ag[ks], bn, acc, 0, 0, 0);
        }
#pragma unroll
        for (int r = 0; r < 4; ++r) {
            int row = m0 + q * 4 + r;
            if (row < n) y1[(long)row * COUT + c] = f2bf(acc[r]);  // b1 cancels in BN
        }
    }
}

__global__ __launch_bounds__(256) void k_gemm1(const int* __restrict__ flag,
        const u16* __restrict__ y0, const u16* __restrict__ agg,
        const void* Wr, const void* Wn,
        u16* y1_bf /*=d_out*/, u16* y1_ws, int ntiles, int n) {
    u16* y1 = *flag ? y1_bf : y1_ws;
    if (*flag) gemm1_impl<true >(y0, agg, Wr, Wn, y1, ntiles, n);
    else       gemm1_impl<false>(y0, agg, Wr, Wn, y1, ntiles, n);
}

// ---------------- BN stats / finalize / apply ----------------
__global__ void k_stats(const int* __restrict__ flag, const u16* __restrict__ pa,
                        const u16* __restrict__ pb, float* __restrict__ sum,
                        float* __restrict__ sumsq, int rows_per_block, int n) {
    const u16* y = *flag ? pa : pb;
    int c = threadIdx.x;  // 128 threads = 128 cols
    int r0 = blockIdx.x * rows_per_block;
    int rend = r0 + rows_per_block; if (rend > n) rend = n;
    float s = 0.f, sq = 0.f;
    for (int r = r0; r < rend; ++r) {
        float v = bf2f(y[(long)r * COUT + c]);
        s += v; sq += v * v;
    }
    atomicAdd(&sum[c], s);
    atomicAdd(&sumsq[c], sq);
}

__global__ void k_bnfin(const int* __restrict__ flag,
                        const float* __restrict__ sum, const float* __restrict__ sumsq,
                        const void* g, const void* be,
                        float* __restrict__ scale, float* __restrict__ shift, int n) {
    int c = threadIdx.x;
    bool bf = (*flag != 0);
    float inv = 1.f / (float)n;
    float mu = sum[c] * inv;
    float var = fmaxf(sumsq[c] * inv - mu * mu, 0.f);  // biased, matches reference
    float gv = bf ? bf2f(((const u16*)g)[c]) : ((const float*)g)[c];
    float bv = bf ? bf2f(((const u16*)be)[c]) : ((const float*)be)[c];
    float sc = gv * rsqrtf(var + BN_EPS);
    scale[c] = sc;
    shift[c] = bv - mu * sc;
}

// y0 <- relu(y0*scale + shift), in place
__global__ void k_bnapply(unsigned int* __restrict__ y, const float* __restrict__ sc,
                          const float* __restrict__ sh, int total2) {
    int stride = gridDim.x * blockDim.x;
    for (int p = blockIdx.x * blockDim.x + threadIdx.x; p < total2; p += stride) {
        unsigned int u = y[p];
        int c0 = (p * 2) & (COUT - 1);
        float v0 = fmaxf(lo16(u) * sc[c0] + sh[c0], 0.f);
        float v1 = fmaxf(hi16(u) * sc[c0 + 1] + sh[c0 + 1], 0.f);
        y[p] = (unsigned int)f2bf(v0) | ((unsigned int)f2bf(v1) << 16);
    }
}

// ---------------- final: out = relu(y1*sc1+sh1 + x@Wlin^T + blin) ---------
template<bool BF>
__device__ __forceinline__ void final_impl(const void* x, const u16* y1,
                                           const void* Wlin, const void* blin,
                                           const float* sc, const float* sh,
                                           void* out, int ntiles, int n) {
    int tile = blockIdx.x * 4 + (threadIdx.x >> 6);
    if (tile >= ntiles) return;
    int lane = threadIdx.x & 63;
    int lr = lane & 15, q = lane >> 4;
    int m0 = tile * 16;
    int ra = m0 + lr; if (ra > n - 1) ra = n - 1;
    short8 ax0 = ld8<BF>(x, (long)ra * CIN + q * 8);
    short8 ax1 = ld8<BF>(x, (long)ra * CIN + 32 + q * 8);
#pragma unroll
    for (int ct = 0; ct < 8; ++ct) {
        int c = ct * 16 + lr;
        short8 b0v = ld8<BF>(Wlin, (long)c * CIN + q * 8);
        short8 b1v = ld8<BF>(Wlin, (long)c * CIN + 32 + q * 8);
        f32x4 acc = {0.f, 0.f, 0.f, 0.f};
        acc = __builtin_amdgcn_mfma_f32_16x16x32_bf16(ax0, b0v, acc, 0, 0, 0);
        acc = __builtin_amdgcn_mfma_f32_16x16x32_bf16(ax1, b1v, acc, 0, 0, 0);
        float bl = ldf<BF>(blin, c);
        float s = sc[c], h = sh[c];
#pragma unroll
        for (int r = 0; r < 4; ++r) {
            int row = m0 + q * 4 + r;
            if (row < n) {
                float v = acc[r] + bl + bf2f(y1[(long)row * COUT + c]) * s + h;
                v = fmaxf(v, 0.f);
                if (BF) ((u16*)out)[(long)row * COUT + c] = f2bf(v);
                else    ((float*)out)[(long)row * COUT + c] = v;
            }
        }
    }
}

__global__ __launch_bounds__(256) void k_final(const int* __restrict__ flag,
        const void* x, const void* Wlin, const void* blin, const u16* y1_ws,
        const float* sc, const float* sh, void* out, int ntiles, int n) {
    if (*flag) final_impl<true >(x, (const u16*)out, Wlin, blin, sc, sh, out, ntiles, n);
    else       final_impl<false>(x, y1_ws, Wlin, blin, sc, sh, out, ntiles, n);
}

extern "C" void kernel_launch(void* const* d_in, const int* in_sizes, int n_in,
                              void* d_out, int out_size, void* d_ws, size_t ws_size,
                              hipStream_t stream) {
    (void)n_in; (void)out_size; (void)ws_size;
    const void* x    = d_in[0];
    const int*  ei   = (const int*)d_in[1];
    const void* Wr0  = d_in[2];
    const void* Wn0  = d_in[3];
    /* b0 dropped: BN-invariant */
    const void* g0   = d_in[5];
    const void* be0  = d_in[6];
    const void* Wr1  = d_in[7];
    const void* Wn1  = d_in[8];
    /* b1 dropped */
    const void* g1   = d_in[10];
    const void* be1  = d_in[11];
    const void* Wlin = d_in[12];
    const void* blin = d_in[13];

    const int N = in_sizes[0] / CIN;
    const int E = in_sizes[1] / 2;
    const int* src = ei;
    const int* dst = ei + E;

    // ---- workspace carve (256B aligned); f32-only region LAST ----
    char* base = (char*)d_ws;
    size_t off = 0;
    auto carve = [&](size_t bytes) -> void* {
        void* p = base + off;
        off = (off + bytes + 255) & ~(size_t)255;
        return p;
    };
    int*   flag      = (int*)carve(256);
    int*   deg       = (int*)carve((size_t)2 * N * sizeof(int));  // deg + cursor
    int*   cursor    = deg + N;
    int*   row_start = (int*)carve((size_t)(N + 1) * sizeof(int));
    int*   blksum    = (int*)carve(4096);
    int*   blkoff    = (int*)carve(4096);
    float* stats     = (float*)carve(512 * sizeof(float));
    float* scsh      = (float*)carve(512 * sizeof(float));
    int*   csr       = (int*)carve((size_t)E * sizeof(int));
    u16*   aggu      = (u16*)carve((size_t)N * COUT * sizeof(u16)); // agg0 (dead after gemm0) aliases agg1
    u16*   y0        = (u16*)carve((size_t)N * COUT * sizeof(u16));
    u16*   y1_ws     = (u16*)carve((size_t)N * COUT * sizeof(u16)); // touched only in f32 mode

    hipMemsetAsync(deg, 0, (size_t)2 * N * sizeof(int), stream);
    hipMemsetAsync(stats, 0, 512 * sizeof(float), stream);

    const int eb  = (E + 255) / 256;
    const int nb1 = (N + 255) / 256;   // 391 <= 512 (scan2 capacity)
    const int nwb = (N + 3) / 4;       // wave-per-node blocks
    const int ntiles = (N + 15) / 16;
    const int gb  = (ntiles + 3) / 4;
    const int rows_pb = 125;
    const int sb  = (N + rows_pb - 1) / rows_pb;

    k_detect<<<1, 64, 0, stream>>>((const unsigned int*)x, flag);

    k_hist <<<eb, 256, 0, stream>>>(dst, deg, E);
    k_scan1<<<nb1, 256, 0, stream>>>(deg, blksum, N);
    k_scan2<<<1, 512, 0, stream>>>(blksum, blkoff, nb1);
    k_scan3<<<nb1, 256, 0, stream>>>(deg, blkoff, row_start, N);
    k_fill <<<eb, 256, 0, stream>>>(src, dst, row_start, cursor, csr, E);

    k_agg0 <<<nwb, 256, 0, stream>>>(flag, x, row_start, csr, aggu, N);
    k_gemm0<<<gb, 256, 0, stream>>>(flag, x, aggu, Wr0, Wn0, y0, ntiles, N);
    k_stats<<<sb, 128, 0, stream>>>(flag, y0, y0, stats, stats + 128, rows_pb, N);
    k_bnfin<<<1, 128, 0, stream>>>(flag, stats, stats + 128, g0, be0, scsh, scsh + 128, N);
    k_bnapply<<<4096, 256, 0, stream>>>((unsigned int*)y0, scsh, scsh + 128, N * CIN);

    k_agg1 <<<nwb, 256, 0, stream>>>(y0, row_start, csr, aggu, N);
    k_gemm1<<<gb, 256, 0, stream>>>(flag, y0, aggu, Wr1, Wn1,
                                    (u16*)d_out, y1_ws, ntiles, N);
    k_stats<<<sb, 128, 0, stream>>>(flag, (const u16*)d_out, y1_ws,
                                    stats + 256, stats + 384, rows_pb, N);
    k_bnfin<<<1, 128, 0, stream>>>(flag, stats + 256, stats + 384, g1, be1,
                                   scsh + 256, scsh + 384, N);

    k_final<<<gb, 256, 0, stream>>>(flag, x, Wlin, blin, y1_ws,
                                    scsh + 256, scsh + 384, d_out, ntiles, N);
}

// Round 4
// 569.604 us; speedup vs baseline: 1.2681x; 1.2681x over previous
//
#include <hip/hip_runtime.h>
#include <stdint.h>

// ResBlock: GraphConv(64->128) -> BN -> ReLU -> GraphConv(128->128) -> BN
//           + (x @ Wlin^T + blin) residual -> ReLU.
// Runtime dtype probe (bf16 vs f32). CSR-by-dst per call.
// R3->R4: dense kernels rebuilt as chunked LDS-staged MFMA (coalesced staging,
// W-frags in registers); BN stats fused into GEMM epilogues; BN0-apply+ReLU
// fused into agg1 gather + gemm1 staging (k_stats x2 and k_bnapply deleted).

#define CIN 64
#define COUT 128
#define BN_EPS 1e-5f

typedef unsigned short u16;
typedef short short8 __attribute__((ext_vector_type(8)));
typedef float f32x4 __attribute__((ext_vector_type(4)));

__device__ __forceinline__ float bf2f(u16 u) {
    union { unsigned int i; float f; } v; v.i = ((unsigned int)u) << 16; return v.f;
}
__device__ __forceinline__ u16 f2bf(float f) {
    union { float f; unsigned int i; } v; v.f = f;
    unsigned int r = v.i + 0x7fffu + ((v.i >> 16) & 1u);  // RNE; finite inputs
    return (u16)(r >> 16);
}
__device__ __forceinline__ float lo16(unsigned int w) { return bf2f((u16)(w & 0xffffu)); }
__device__ __forceinline__ float hi16(unsigned int w) { return bf2f((u16)(w >> 16)); }

template<bool BF> __device__ __forceinline__ float ldf(const void* p, long i) {
    if (BF) return bf2f(((const u16*)p)[i]);
    return ((const float*)p)[i];
}
template<bool BF> __device__ __forceinline__ short8 ld8(const void* p, long i) {
    if (BF) return *(const short8*)((const u16*)p + i);
    const float* f = (const float*)p + i;
    short8 r;
#pragma unroll
    for (int j = 0; j < 8; ++j) r[j] = (short)f2bf(f[j]);
    return r;
}

// ---- coalesced 64-row chunk staging into padded LDS (bf16 in LDS) --------
// RL = row length in elements (64 or 128). 256 threads.
template<bool BF, int RL>
__device__ __forceinline__ void stage_tile(const void* g, long first_row,
                                           u16* lds, int stride, int col_off,
                                           int n, int tid) {
    if (BF) {
        const int SPR = RL / 8;                 // 16B segments per row
        const int NPT = 64 * SPR / 256;         // segments per thread
#pragma unroll
        for (int i = 0; i < NPT; ++i) {
            int s = tid + i * 256;
            int row = s / SPR, within = s % SPR;
            long rg = first_row + row; if (rg > n - 1) rg = n - 1;
            short8 v = *(const short8*)((const u16*)g + rg * RL + within * 8);
            *(short8*)(lds + row * stride + col_off + within * 8) = v;
        }
    } else {
        const int SPR = RL / 4;                 // float4 segments per row
        const int NPT = 64 * SPR / 256;
#pragma unroll
        for (int i = 0; i < NPT; ++i) {
            int s = tid + i * 256;
            int row = s / SPR, within = s % SPR;
            long rg = first_row + row; if (rg > n - 1) rg = n - 1;
            float4 v = *(const float4*)((const float*)g + rg * RL + within * 4);
            u16* d = lds + row * stride + col_off + within * 4;
            d[0] = f2bf(v.x); d[1] = f2bf(v.y); d[2] = f2bf(v.z); d[3] = f2bf(v.w);
        }
    }
}

// stage y0 (bf16) with fused BN0-apply + ReLU
__device__ __forceinline__ void stage_y0p(const u16* y0, long first_row,
                                          u16* lds, int stride,
                                          const float* __restrict__ sc,
                                          const float* __restrict__ sh,
                                          int n, int tid) {
#pragma unroll
    for (int i = 0; i < 4; ++i) {
        int s = tid + i * 256;
        int row = s >> 4, within = s & 15;
        long rg = first_row + row; if (rg > n - 1) rg = n - 1;
        short8 v = *(const short8*)(y0 + rg * COUT + within * 8);
        int c = within * 8;
        short8 o;
#pragma unroll
        for (int j = 0; j < 8; ++j)
            o[j] = (short)f2bf(fmaxf(bf2f((u16)v[j]) * sc[c + j] + sh[c + j], 0.f));
        *(short8*)(lds + row * stride + within * 8) = o;
    }
}

// ---------------- dtype detection ----------------
__global__ void k_detect(const unsigned int* __restrict__ x, int* __restrict__ flag) {
    int lane = threadIdx.x;  // 64
    int cnt = 0;
#pragma unroll
    for (int i = 0; i < 8; ++i) {
        unsigned int w = x[lane * 8 + i];
        unsigned int e0 = (w >> 7) & 0xFFu, e1 = (w >> 23) & 0xFFu;
        cnt += (e0 >= 0x60u && e0 <= 0x8Eu);
        cnt += (e1 >= 0x60u && e1 <= 0x8Eu);
    }
    for (int o = 32; o; o >>= 1) cnt += __shfl_down(cnt, o);
    if (lane == 0) *flag = (cnt > 850) ? 1 : 0;   // 1 => bf16
}

// ---------------- CSR build ----------------
__global__ void k_hist(const int* __restrict__ dst, int* __restrict__ deg, int E) {
    int e = blockIdx.x * blockDim.x + threadIdx.x;
    if (e < E) atomicAdd(&deg[dst[e]], 1);
}

__global__ void k_scan1(const int* __restrict__ deg, int* __restrict__ blksum, int n) {
    __shared__ int s[256];
    int t = threadIdx.x, i = blockIdx.x * 256 + t;
    int v = (i < n) ? deg[i] : 0;
    s[t] = v; __syncthreads();
    for (int o = 1; o < 256; o <<= 1) {
        int u = (t >= o) ? s[t - o] : 0;
        __syncthreads(); s[t] += u; __syncthreads();
    }
    if (t == 255) blksum[blockIdx.x] = s[255];
}

__global__ void k_scan2(const int* __restrict__ blksum, int* __restrict__ blkoff, int nb) {
    __shared__ int s[512];
    int t = threadIdx.x;
    int v = (t < nb) ? blksum[t] : 0;
    s[t] = v; __syncthreads();
    for (int o = 1; o < 512; o <<= 1) {
        int u = (t >= o) ? s[t - o] : 0;
        __syncthreads(); s[t] += u; __syncthreads();
    }
    if (t < nb) blkoff[t] = s[t] - v;  // exclusive
}

__global__ void k_scan3(const int* __restrict__ deg, const int* __restrict__ blkoff,
                        int* __restrict__ row_start, int n) {
    __shared__ int s[256];
    int t = threadIdx.x, i = blockIdx.x * 256 + t;
    int v = (i < n) ? deg[i] : 0;
    s[t] = v; __syncthreads();
    for (int o = 1; o < 256; o <<= 1) {
        int u = (t >= o) ? s[t - o] : 0;
        __syncthreads(); s[t] += u; __syncthreads();
    }
    int base = blkoff[blockIdx.x];
    if (i < n) row_start[i] = base + s[t] - v;
    if (i == n - 1) row_start[n] = base + s[t];
}

__global__ void k_fill(const int* __restrict__ src, const int* __restrict__ dst,
                       const int* __restrict__ row_start, int* __restrict__ cursor,
                       int* __restrict__ csr, int E) {
    int e = blockIdx.x * blockDim.x + threadIdx.x;
    if (e < E) {
        int d = dst[e];
        int p = atomicAdd(&cursor[d], 1);
        csr[row_start[d] + p] = src[e];
    }
}

// ---------------- aggregation (pull, wave per node, coalesced rows) -------
template<bool BF>
__device__ __forceinline__ void agg0_impl(const void* x, const int* rs, const int* csr,
                                          u16* agg, int n) {
    int i = blockIdx.x * 4 + (threadIdx.x >> 6);
    if (i >= n) return;
    int lane = threadIdx.x & 63;
    int h = lane >> 5, cp = lane & 31;
    int b = rs[i], e = rs[i + 1];
    float a0 = 0.f, a1 = 0.f, b0 = 0.f, b1 = 0.f;
    int t = b + h;
    for (; t + 2 < e; t += 4) {
        int j0 = csr[t], j1 = csr[t + 2];
        if (BF) {
            unsigned int w0 = ((const unsigned int*)x)[(long)j0 * 32 + cp];
            unsigned int w1 = ((const unsigned int*)x)[(long)j1 * 32 + cp];
            a0 += lo16(w0); a1 += hi16(w0);
            b0 += lo16(w1); b1 += hi16(w1);
        } else {
            float2 w0 = ((const float2*)x)[(long)j0 * 32 + cp];
            float2 w1 = ((const float2*)x)[(long)j1 * 32 + cp];
            a0 += w0.x; a1 += w0.y;
            b0 += w1.x; b1 += w1.y;
        }
    }
    for (; t < e; t += 2) {
        int j0 = csr[t];
        if (BF) {
            unsigned int w0 = ((const unsigned int*)x)[(long)j0 * 32 + cp];
            a0 += lo16(w0); a1 += hi16(w0);
        } else {
            float2 w0 = ((const float2*)x)[(long)j0 * 32 + cp];
            a0 += w0.x; a1 += w0.y;
        }
    }
    a0 += b0; a1 += b1;
    a0 += __shfl_xor(a0, 32);
    a1 += __shfl_xor(a1, 32);
    if (h == 0) {
        unsigned int o = (unsigned int)f2bf(a0) | ((unsigned int)f2bf(a1) << 16);
        ((unsigned int*)agg)[(long)i * 32 + cp] = o;
    }
}

__global__ __launch_bounds__(256) void k_agg0(const int* __restrict__ flag,
        const void* x, const int* __restrict__ rs, const int* __restrict__ csr,
        u16* __restrict__ agg, int n) {
    if (*flag) agg0_impl<true >(x, rs, csr, agg, n);
    else       agg0_impl<false>(x, rs, csr, agg, n);
}

// agg1: gathers relu(bn0(y0_raw)); scale/shift applied on the fly.
__global__ __launch_bounds__(256) void k_agg1(const u16* __restrict__ y0,
        const int* __restrict__ rs, const int* __restrict__ csr,
        const float* __restrict__ scale, const float* __restrict__ shift,
        u16* __restrict__ agg, int n) {
    int i = blockIdx.x * 4 + (threadIdx.x >> 6);
    if (i >= n) return;
    int lane = threadIdx.x & 63;
    int c0 = 2 * lane;
    float s0 = scale[c0], s1 = scale[c0 + 1];
    float h0 = shift[c0], h1 = shift[c0 + 1];
    const unsigned int* y32 = (const unsigned int*)y0;
    int b = rs[i], e = rs[i + 1];
    float a0 = 0.f, a1 = 0.f, b0 = 0.f, b1 = 0.f;
    float c0a = 0.f, c1a = 0.f, d0 = 0.f, d1 = 0.f;
    int t = b;
    for (; t + 4 <= e; t += 4) {
        int j0 = csr[t], j1 = csr[t + 1], j2 = csr[t + 2], j3 = csr[t + 3];
        unsigned int w0 = y32[(long)j0 * 64 + lane];
        unsigned int w1 = y32[(long)j1 * 64 + lane];
        unsigned int w2 = y32[(long)j2 * 64 + lane];
        unsigned int w3 = y32[(long)j3 * 64 + lane];
        a0  += fmaxf(lo16(w0) * s0 + h0, 0.f); a1  += fmaxf(hi16(w0) * s1 + h1, 0.f);
        b0  += fmaxf(lo16(w1) * s0 + h0, 0.f); b1  += fmaxf(hi16(w1) * s1 + h1, 0.f);
        c0a += fmaxf(lo16(w2) * s0 + h0, 0.f); c1a += fmaxf(hi16(w2) * s1 + h1, 0.f);
        d0  += fmaxf(lo16(w3) * s0 + h0, 0.f); d1  += fmaxf(hi16(w3) * s1 + h1, 0.f);
    }
    for (; t < e; ++t) {
        unsigned int w0 = y32[(long)csr[t] * 64 + lane];
        a0 += fmaxf(lo16(w0) * s0 + h0, 0.f); a1 += fmaxf(hi16(w0) * s1 + h1, 0.f);
    }
    float s0t = (a0 + b0) + (c0a + d0);
    float s1t = (a1 + b1) + (c1a + d1);
    ((unsigned int*)agg)[(long)i * 64 + lane] =
        (unsigned int)f2bf(s0t) | ((unsigned int)f2bf(s1t) << 16);
}

// ---------------- GEMM0: y0 = [x|agg0] @ [Wr0;Wn0]^T, fused stats ----------
// One block per 64-row chunk. Wave w owns output cols [2w*16, 2w*16+32).
template<bool BF>
__device__ __forceinline__ void gemm0_impl(const void* x, const u16* agg,
                                           const void* Wr, const void* Wn,
                                           u16* y0, float* sum, float* sumsq,
                                           int n, u16* lds) {
    const int ST = 130;  // padded LDS row stride (u16) -> mild bank conflicts
    int tid = threadIdx.x;
    int wave = tid >> 6, lane = tid & 63, lr = lane & 15, q = lane >> 4;
    long chunk0 = (long)blockIdx.x * 64;

    short8 wf[2][4];
#pragma unroll
    for (int i = 0; i < 2; ++i) {
        int c = (2 * wave + i) * 16 + lr;
#pragma unroll
        for (int ks = 0; ks < 4; ++ks) {
            const void* W = (ks < 2) ? Wr : Wn;
            wf[i][ks] = ld8<BF>(W, (long)c * CIN + (ks & 1) * 32 + q * 8);
        }
    }
    stage_tile<BF, 64>(x, chunk0, lds, ST, 0, n, tid);
    stage_tile<true, 64>(agg, chunk0, lds, ST, 64, n, tid);
    __syncthreads();

    float st[2] = {0.f, 0.f}, sq[2] = {0.f, 0.f};
#pragma unroll
    for (int t = 0; t < 4; ++t) {
        short8 a[4];
#pragma unroll
        for (int ks = 0; ks < 4; ++ks)
            a[ks] = *(const short8*)(lds + (t * 16 + lr) * ST + ks * 32 + q * 8);
#pragma unroll
        for (int i = 0; i < 2; ++i) {
            f32x4 acc = {0.f, 0.f, 0.f, 0.f};
#pragma unroll
            for (int ks = 0; ks < 4; ++ks)
                acc = __builtin_amdgcn_mfma_f32_16x16x32_bf16(a[ks], wf[i][ks], acc, 0, 0, 0);
            int c = (2 * wave + i) * 16 + lr;
#pragma unroll
            for (int r = 0; r < 4; ++r) {
                long row = chunk0 + t * 16 + q * 4 + r;
                if (row < n) {
                    y0[row * COUT + c] = f2bf(acc[r]);   // b0 cancels in BN
                    st[i] += acc[r]; sq[i] += acc[r] * acc[r];
                }
            }
        }
    }
#pragma unroll
    for (int i = 0; i < 2; ++i) {
        st[i] += __shfl_xor(st[i], 16); st[i] += __shfl_xor(st[i], 32);
        sq[i] += __shfl_xor(sq[i], 16); sq[i] += __shfl_xor(sq[i], 32);
    }
    if (q == 0) {
#pragma unroll
        for (int i = 0; i < 2; ++i) {
            int c = (2 * wave + i) * 16 + lr;
            atomicAdd(&sum[c], st[i]);
            atomicAdd(&sumsq[c], sq[i]);
        }
    }
}

__global__ __launch_bounds__(256) void k_gemm0(const int* __restrict__ flag,
        const void* x, const u16* __restrict__ agg, const void* Wr, const void* Wn,
        u16* __restrict__ y0, float* __restrict__ sum, float* __restrict__ sumsq, int n) {
    __shared__ u16 lds[64 * 130];
    if (*flag) gemm0_impl<true >(x, agg, Wr, Wn, y0, sum, sumsq, n, lds);
    else       gemm0_impl<false>(x, agg, Wr, Wn, y0, sum, sumsq, n, lds);
}

// ---------------- GEMM1: y1 = [relu(bn0(y0))|agg1] @ [Wr1;Wn1]^T, stats ----
template<bool BF>
__device__ __forceinline__ void gemm1_impl(const u16* y0, const u16* agg,
                                           const void* Wr, const void* Wn,
                                           const float* sc0, const float* sh0,
                                           u16* y1, float* sum, float* sumsq,
                                           int n, u16* lds) {
    const int ST = 258;
    int tid = threadIdx.x;
    int wave = tid >> 6, lane = tid & 63, lr = lane & 15, q = lane >> 4;
    long chunk0 = (long)blockIdx.x * 64;

    short8 wf[2][8];
#pragma unroll
    for (int i = 0; i < 2; ++i) {
        int c = (2 * wave + i) * 16 + lr;
#pragma unroll
        for (int ks = 0; ks < 8; ++ks) {
            const void* W = (ks < 4) ? Wr : Wn;
            wf[i][ks] = ld8<BF>(W, (long)c * COUT + (ks & 3) * 32 + q * 8);
        }
    }
    stage_y0p(y0, chunk0, lds, ST, sc0, sh0, n, tid);          // cols 0..127 transformed
    stage_tile<true, 128>(agg, chunk0, lds, ST, 128, n, tid);  // cols 128..255
    __syncthreads();

    float st[2] = {0.f, 0.f}, sq[2] = {0.f, 0.f};
#pragma unroll
    for (int t = 0; t < 4; ++t) {
        short8 a[8];
#pragma unroll
        for (int ks = 0; ks < 8; ++ks)
            a[ks] = *(const short8*)(lds + (t * 16 + lr) * ST + ks * 32 + q * 8);
#pragma unroll
        for (int i = 0; i < 2; ++i) {
            f32x4 acc = {0.f, 0.f, 0.f, 0.f};
#pragma unroll
            for (int ks = 0; ks < 8; ++ks)
                acc = __builtin_amdgcn_mfma_f32_16x16x32_bf16(a[ks], wf[i][ks], acc, 0, 0, 0);
            int c = (2 * wave + i) * 16 + lr;
#pragma unroll
            for (int r = 0; r < 4; ++r) {
                long row = chunk0 + t * 16 + q * 4 + r;
                if (row < n) {
                    y1[row * COUT + c] = f2bf(acc[r]);   // b1 cancels in BN
                    st[i] += acc[r]; sq[i] += acc[r] * acc[r];
                }
            }
        }
    }
#pragma unroll
    for (int i = 0; i < 2; ++i) {
        st[i] += __shfl_xor(st[i], 16); st[i] += __shfl_xor(st[i], 32);
        sq[i] += __shfl_xor(sq[i], 16); sq[i] += __shfl_xor(sq[i], 32);
    }
    if (q == 0) {
#pragma unroll
        for (int i = 0; i < 2; ++i) {
            int c = (2 * wave + i) * 16 + lr;
            atomicAdd(&sum[c], st[i]);
            atomicAdd(&sumsq[c], sq[i]);
        }
    }
}

__global__ __launch_bounds__(256) void k_gemm1(const int* __restrict__ flag,
        const u16* __restrict__ y0, const u16* __restrict__ agg,
        const void* Wr, const void* Wn,
        const float* __restrict__ sc0, const float* __restrict__ sh0,
        u16* y1_bf /*=d_out*/, u16* y1_ws,
        float* __restrict__ sum, float* __restrict__ sumsq, int n) {
    __shared__ u16 lds[64 * 258];
    u16* y1 = *flag ? y1_bf : y1_ws;
    if (*flag) gemm1_impl<true >(y0, agg, Wr, Wn, sc0, sh0, y1, sum, sumsq, n, lds);
    else       gemm1_impl<false>(y0, agg, Wr, Wn, sc0, sh0, y1, sum, sumsq, n, lds);
}

// ---------------- BN finalize (tiny) ----------------
__global__ void k_bnfin(const int* __restrict__ flag,
                        const float* __restrict__ sum, const float* __restrict__ sumsq,
                        const void* g, const void* be,
                        float* __restrict__ scale, float* __restrict__ shift, int n) {
    int c = threadIdx.x;
    bool bf = (*flag != 0);
    float inv = 1.f / (float)n;
    float mu = sum[c] * inv;
    float var = fmaxf(sumsq[c] * inv - mu * mu, 0.f);  // biased, matches reference
    float gv = bf ? bf2f(((const u16*)g)[c]) : ((const float*)g)[c];
    float bv = bf ? bf2f(((const u16*)be)[c]) : ((const float*)be)[c];
    float sc = gv * rsqrtf(var + BN_EPS);
    scale[c] = sc;
    shift[c] = bv - mu * sc;
}

// ---------------- final: out = relu(bn1(y1) + x@Wlin^T + blin) ------------
template<bool BF>
__device__ __forceinline__ void final_impl(const void* x, const u16* y1,
                                           const void* Wlin, const void* blin,
                                           const float* sc, const float* sh,
                                           void* out, int n, u16* lds) {
    const int ST = 194;  // 64 x-cols + 128 y1-cols + 2 pad
    int tid = threadIdx.x;
    int wave = tid >> 6, lane = tid & 63, lr = lane & 15, q = lane >> 4;
    long chunk0 = (long)blockIdx.x * 64;

    short8 wf[2][2];
    float blc[2], scc[2], shc[2];
#pragma unroll
    for (int i = 0; i < 2; ++i) {
        int c = (2 * wave + i) * 16 + lr;
#pragma unroll
        for (int ks = 0; ks < 2; ++ks)
            wf[i][ks] = ld8<BF>(Wlin, (long)c * CIN + ks * 32 + q * 8);
        blc[i] = ldf<BF>(blin, c);
        scc[i] = sc[c]; shc[i] = sh[c];
    }
    stage_tile<BF, 64>(x, chunk0, lds, ST, 0, n, tid);
    stage_tile<true, 128>(y1, chunk0, lds, ST, 64, n, tid);
    __syncthreads();

#pragma unroll
    for (int t = 0; t < 4; ++t) {
        short8 a[2];
#pragma unroll
        for (int ks = 0; ks < 2; ++ks)
            a[ks] = *(const short8*)(lds + (t * 16 + lr) * ST + ks * 32 + q * 8);
#pragma unroll
        for (int i = 0; i < 2; ++i) {
            f32x4 acc = {0.f, 0.f, 0.f, 0.f};
            acc = __builtin_amdgcn_mfma_f32_16x16x32_bf16(a[0], wf[i][0], acc, 0, 0, 0);
            acc = __builtin_amdgcn_mfma_f32_16x16x32_bf16(a[1], wf[i][1], acc, 0, 0, 0);
            int c = (2 * wave + i) * 16 + lr;
#pragma unroll
            for (int r = 0; r < 4; ++r) {
                long row = chunk0 + t * 16 + q * 4 + r;
                if (row < n) {
                    float yv = bf2f(lds[(t * 16 + q * 4 + r) * ST + 64 + c]);
                    float v = acc[r] + blc[i] + yv * scc[i] + shc[i];
                    v = fmaxf(v, 0.f);
                    if (BF) ((u16*)out)[row * COUT + c] = f2bf(v);
                    else    ((float*)out)[row * COUT + c] = v;
                }
            }
        }
    }
}

__global__ __launch_bounds__(256) void k_final(const int* __restrict__ flag,
        const void* x, const void* Wlin, const void* blin,
        const u16* y1_bf /*=d_out*/, const u16* y1_ws,
        const float* __restrict__ sc, const float* __restrict__ sh,
        void* out, int n) {
    __shared__ u16 lds[64 * 194];
    const u16* y1 = *flag ? y1_bf : y1_ws;
    if (*flag) final_impl<true >(x, y1, Wlin, blin, sc, sh, out, n, lds);
    else       final_impl<false>(x, y1, Wlin, blin, sc, sh, out, n, lds);
}

extern "C" void kernel_launch(void* const* d_in, const int* in_sizes, int n_in,
                              void* d_out, int out_size, void* d_ws, size_t ws_size,
                              hipStream_t stream) {
    (void)n_in; (void)out_size; (void)ws_size;
    const void* x    = d_in[0];
    const int*  ei   = (const int*)d_in[1];
    const void* Wr0  = d_in[2];
    const void* Wn0  = d_in[3];
    /* b0 dropped: BN-invariant */
    const void* g0   = d_in[5];
    const void* be0  = d_in[6];
    const void* Wr1  = d_in[7];
    const void* Wn1  = d_in[8];
    /* b1 dropped */
    const void* g1   = d_in[10];
    const void* be1  = d_in[11];
    const void* Wlin = d_in[12];
    const void* blin = d_in[13];

    const int N = in_sizes[0] / CIN;
    const int E = in_sizes[1] / 2;
    const int* src = ei;
    const int* dst = ei + E;

    // ---- workspace carve (256B aligned); f32-only region LAST ----
    char* base = (char*)d_ws;
    size_t off = 0;
    auto carve = [&](size_t bytes) -> void* {
        void* p = base + off;
        off = (off + bytes + 255) & ~(size_t)255;
        return p;
    };
    int*   flag      = (int*)carve(256);
    int*   deg       = (int*)carve((size_t)2 * N * sizeof(int));  // deg + cursor
    int*   cursor    = deg + N;
    int*   row_start = (int*)carve((size_t)(N + 1) * sizeof(int));
    int*   blksum    = (int*)carve(4096);
    int*   blkoff    = (int*)carve(4096);
    float* stats     = (float*)carve(512 * sizeof(float));  // sum0,sq0,sum1,sq1
    float* scsh      = (float*)carve(512 * sizeof(float));  // scale0,shift0,scale1,shift1
    int*   csr       = (int*)carve((size_t)E * sizeof(int));
    u16*   aggu      = (u16*)carve((size_t)N * COUT * sizeof(u16)); // agg0 (dead after gemm0) aliases agg1
    u16*   y0        = (u16*)carve((size_t)N * COUT * sizeof(u16));
    u16*   y1_ws     = (u16*)carve((size_t)N * COUT * sizeof(u16)); // touched only in f32 mode

    hipMemsetAsync(deg, 0, (size_t)2 * N * sizeof(int), stream);
    hipMemsetAsync(stats, 0, 512 * sizeof(float), stream);

    const int eb  = (E + 255) / 256;
    const int nb1 = (N + 255) / 256;   // 391 <= 512 (scan2 capacity)
    const int nwb = (N + 3) / 4;       // wave-per-node blocks
    const int nch = (N + 63) / 64;     // 64-row chunks for dense kernels

    k_detect<<<1, 64, 0, stream>>>((const unsigned int*)x, flag);

    k_hist <<<eb, 256, 0, stream>>>(dst, deg, E);
    k_scan1<<<nb1, 256, 0, stream>>>(deg, blksum, N);
    k_scan2<<<1, 512, 0, stream>>>(blksum, blkoff, nb1);
    k_scan3<<<nb1, 256, 0, stream>>>(deg, blkoff, row_start, N);
    k_fill <<<eb, 256, 0, stream>>>(src, dst, row_start, cursor, csr, E);

    k_agg0 <<<nwb, 256, 0, stream>>>(flag, x, row_start, csr, aggu, N);
    k_gemm0<<<nch, 256, 0, stream>>>(flag, x, aggu, Wr0, Wn0, y0,
                                     stats, stats + 128, N);
    k_bnfin<<<1, 128, 0, stream>>>(flag, stats, stats + 128, g0, be0,
                                   scsh, scsh + 128, N);

    k_agg1 <<<nwb, 256, 0, stream>>>(y0, row_start, csr, scsh, scsh + 128, aggu, N);
    k_gemm1<<<nch, 256, 0, stream>>>(flag, y0, aggu, Wr1, Wn1, scsh, scsh + 128,
                                     (u16*)d_out, y1_ws, stats + 256, stats + 384, N);
    k_bnfin<<<1, 128, 0, stream>>>(flag, stats + 256, stats + 384, g1, be1,
                                   scsh + 256, scsh + 384, N);

    k_final<<<nch, 256, 0, stream>>>(flag, x, Wlin, blin,
                                     (const u16*)d_out, y1_ws,
                                     scsh + 256, scsh + 384, d_out, N);
}